// Round 14
// baseline (123.020 us; speedup 1.0000x reference)
//
#include <hip/hip_runtime.h>
#include <cstddef>
#include <cstdint>

// SupConLoss fused: MFMA + fragment-major loads + j-parity wave split +
// class-id mask (4KB L1-resident table) + cross-iteration aJ slice-0
// prefetch. launch_bounds(256,4) pins 4 waves/SIMD (VGPR cap 128).
// Separate loss kernel (NO device fences -- a per-block __threadfence ticket
// cost 90us in L2 writebacks on the non-coherent per-XCD L2s).
//
// Math (row-max cancels exactly):
//   num_i = sum_{j!=i} e^{-adc_ij} D2_j, s_i = sum_{j!=i} e^{-adc_ij}
//   den_i = sum_{j!=i} e^{+adc_ij},      a_i = sum m_ij adc_ij, b_i = sum m_ij
//   D_hat = softmax(0.7*(D2 - num/s) + 0.3*L2); loss = -mean((a - b*log den)/(b+1e-5))
// mask[i][j] = (cls[i&2047]==cls[j&2047]); cls[r] = first-set column of mask
// row r (diagonal guarantees existence).
//
//   XF[tile16][ks4][lane64][8]     : X*(1/sqrt(T)) bf16 fragments
//   DF[jtile64][n8*ks2][lane64][8] : D2^T bf16 fragments (PV B operand)
//   cls[2048]                      : u16 class representatives

namespace {
constexpr int   kN   = 4096;
constexpr int   kB   = 2048;
constexpr int   kD   = 128;
constexpr float kSc  = 3.77964473f;   // 1/sqrt(0.07); kSc*kSc = 1/T
}

typedef __attribute__((ext_vector_type(8))) short bf16x8;
typedef __attribute__((ext_vector_type(4))) float f32x4;
typedef __attribute__((ext_vector_type(4))) uint  u32x4;
typedef unsigned long long ull;

union U16B { uint4 u; bf16x8 v; };

__device__ __forceinline__ ushort f2bf(float x) {  // RNE f32->bf16 (finite)
    union { float f; uint u; } v; v.f = x;
    return (ushort)((v.u + 0x7FFFu + ((v.u >> 16) & 1u)) >> 16);
}
__device__ __forceinline__ uint pack2(float a, float b) {
    return (uint)f2bf(a) | ((uint)f2bf(b) << 16);
}
__device__ __forceinline__ uint cvtpk(float a, float b) {  // {lo=bf(a), hi=bf(b)}
    uint r;
    asm("v_cvt_pk_bf16_f32 %0, %1, %2" : "=v"(r) : "v"(a), "v"(b));
    return r;
}
__device__ __forceinline__ float bf2f(ushort u) {
    union { float f; uint x; } v; v.x = (uint)u << 16; return v.f;
}

// ---- prep: b<64: XF ; b<128: DF (LDS transpose) ; b<192: cls extraction ----
__global__ __launch_bounds__(256)
void supcon_prep(const float* __restrict__ feats, const float* __restrict__ Dp,
                 const float* __restrict__ maskp,
                 ushort* __restrict__ XF, ushort* __restrict__ DF,
                 ushort* __restrict__ cls)
{
    __shared__ float sh[64][129];
    const int b = blockIdx.x, t = threadIdx.x;
    const int lane = t & 63, l15 = lane & 15, lg = lane >> 4;

    if (b < 64) {
        const int tile = b * 4 + (t >> 6);
        const int i = tile * 16 + l15;
        const float* rp = feats + (size_t)(i & (kB - 1)) * 256 + (i >> 11) * 128;
        #pragma unroll
        for (int ks = 0; ks < 4; ++ks) {
            const float4 v0 = *(const float4*)(rp + ks * 32 + lg * 8);
            const float4 v1 = *(const float4*)(rp + ks * 32 + lg * 8 + 4);
            uint4 u;
            u.x = pack2(v0.x * kSc, v0.y * kSc); u.y = pack2(v0.z * kSc, v0.w * kSc);
            u.z = pack2(v1.x * kSc, v1.y * kSc); u.w = pack2(v1.z * kSc, v1.w * kSc);
            *(uint4*)&XF[(size_t)tile * 2048 + ks * 512 + lane * 8] = u;
        }
    } else if (b < 128) {
        const int jt = b - 64;
        const int r = t >> 2, c0 = (t & 3) * 32;
        const float* dp = Dp + (size_t)((jt * 64 + r) & (kB - 1)) * kD + c0;
        #pragma unroll
        for (int q = 0; q < 8; ++q) {
            const float4 v = *(const float4*)(dp + q * 4);
            sh[r][c0 + q * 4 + 0] = v.x; sh[r][c0 + q * 4 + 1] = v.y;
            sh[r][c0 + q * 4 + 2] = v.z; sh[r][c0 + q * 4 + 3] = v.w;
        }
        __syncthreads();
        #pragma unroll
        for (int k4 = 0; k4 < 4; ++k4) {
            const int U = k4 * 256 + t;
            const int nk = U >> 6;
            const int n = nk >> 1, ks = nk & 1;
            ushort e[8];
            #pragma unroll
            for (int ee = 0; ee < 8; ++ee)
                e[ee] = f2bf(sh[ks * 32 + lg * 8 + ee][n * 16 + l15]);
            uint4 u;
            u.x = (uint)e[0] | ((uint)e[1] << 16);
            u.y = (uint)e[2] | ((uint)e[3] << 16);
            u.z = (uint)e[4] | ((uint)e[5] << 16);
            u.w = (uint)e[6] | ((uint)e[7] << 16);
            *(uint4*)&DF[(size_t)jt * 8192 + (size_t)U * 8] = u;
        }
    } else {
        // cls: first-set column per mask row (8 rows per wave)
        const int wid = (b - 128) * 4 + (t >> 6);   // 0..255
        for (int rr = 0; rr < 8; ++rr) {
            const int row = wid * 8 + rr;
            const float* mrow = maskp + (size_t)row * kN;
            int found = -1;
            for (int q = 0; q < 8 && found < 0; ++q) {
                const float4 v = *(const float4*)(mrow + q * 256 + lane * 4);
                const ull b0 = __ballot(v.x != 0.f);
                const ull b1 = __ballot(v.y != 0.f);
                const ull b2 = __ballot(v.z != 0.f);
                const ull b3 = __ballot(v.w != 0.f);
                const ull any = b0 | b1 | b2 | b3;
                if (any) {
                    const int l0 = (int)__builtin_ctzll(any);
                    const int e0 = ((b0 >> l0) & 1ull) ? 0 : ((b1 >> l0) & 1ull) ? 1
                                 : ((b2 >> l0) & 1ull) ? 2 : 3;
                    found = q * 256 + l0 * 4 + e0;
                }
            }
            if (lane == 0) cls[row] = (ushort)found;
        }
    }
}

// ---- main: 256 thr = (2 i-subtiles) x (2 j-parities), 32 i-rows/block ----
// launch_bounds(256,4): min 4 waves/EU -> VGPR cap 128, pins 4 waves/SIMD.
__global__ __launch_bounds__(256, 4)
void supcon_main(const ushort* __restrict__ XF,
                 const ushort* __restrict__ DF,
                 const ushort* __restrict__ cls,
                 ushort* __restrict__ num_bf,    // [nchunk][4096][128] bf16
                 float* __restrict__ s_part,
                 float* __restrict__ d_part,
                 float* __restrict__ a_part,
                 float* __restrict__ b_part,
                 int jt_per)                     // must be even
{
    __shared__ float RED[2][16][132];
    __shared__ float SC[2][4][16];

    const int t    = threadIdx.x;
    const int lane = t & 63;
    const int l15  = lane & 15;
    const int lg   = lane >> 4;
    const int w    = t >> 6;
    const int ip   = w >> 1;            // i-subtile
    const int jp   = w & 1;             // j-parity
    const int bx   = blockIdx.x;        // 0..127 (32-row i-block)
    const int I0w  = bx * 32 + ip * 16;
    const int gi   = I0w + l15;
    const int chunk = blockIdx.y;
    const int Jbase = chunk * (jt_per * 64);

    bf16x8 bI[4];
    {
        const size_t xfI = (size_t)(bx * 2 + ip) * 2048 + lane * 8;
        #pragma unroll
        for (int ks = 0; ks < 4; ++ks)
            bI[ks] = *(const bf16x8*)&XF[xfI + ks * 512];
    }
    const ushort cls_i = cls[gi & (kB - 1)];

    f32x4 numacc[8];
    #pragma unroll
    for (int n = 0; n < 8; ++n) numacc[n] = (f32x4){0.f, 0.f, 0.f, 0.f};
    float s_acc = 0.f, d_acc = 0.f, a_acc = 0.f, b_acc = 0.f;

    const int srcA = l15 | (((lg << 1) & 3) << 4);
    const int srcB = l15 | ((((lg << 1) | 1) & 3) << 4);
    const bool hiSel = (lg >= 2);

    ushort4 cvn[4];
    bf16x8 aJn[4];                       // next tile's aJ slice-0 (prefetch)
    {
        const int jb = (Jbase + jp * 64) & (kB - 1);
        #pragma unroll
        for (int m = 0; m < 4; ++m)
            cvn[m] = *(const ushort4*)&cls[jb + m * 16 + lg * 4];
        const size_t xfJ0 = (size_t)((Jbase + jp * 64) >> 4) * 2048 + lane * 8;
        #pragma unroll
        for (int m = 0; m < 4; ++m)
            aJn[m] = *(const bf16x8*)&XF[xfJ0 + (size_t)m * 2048];
    }

    for (int jt = jp; jt < jt_per; jt += 2) {
        const int J0 = Jbase + jt * 64;

        // ---- QK^T: slice-0 comes from cross-iteration prefetch ----
        f32x4 acc[4];
        #pragma unroll
        for (int m = 0; m < 4; ++m) acc[m] = (f32x4){0.f, 0.f, 0.f, 0.f};
        const size_t xfJ = (size_t)(J0 >> 4) * 2048 + lane * 8;
        bf16x8 aJ2[2][4];
        #pragma unroll
        for (int m = 0; m < 4; ++m)
            aJ2[0][m] = aJn[m];
        #pragma unroll
        for (int ks = 0; ks < 4; ++ks) {
            if (ks < 3) {
                #pragma unroll
                for (int m = 0; m < 4; ++m)
                    aJ2[(ks + 1) & 1][m] =
                        *(const bf16x8*)&XF[xfJ + (size_t)m * 2048 + (ks + 1) * 512];
            }
            #pragma unroll
            for (int m = 0; m < 4; ++m)
                acc[m] = __builtin_amdgcn_mfma_f32_16x16x32_bf16(
                    aJ2[ks & 1][m], bI[ks], acc[m], 0, 0, 0);
        }

        // ---- first-half bD ----
        const size_t dfJ = (size_t)(J0 >> 6) * 8192 + lane * 8;
        bf16x8 bDa[4][2];
        #pragma unroll
        for (int n = 0; n < 4; ++n)
            #pragma unroll
            for (int ks = 0; ks < 2; ++ks)
                bDa[n][ks] = *(const bf16x8*)&DF[dfJ + (n * 2 + ks) * 512];

        // ---- exp, scalar partials, pack P (adc = acc, pre-scaled X) ----
        const bool isDiag = ((J0 >> 6) == (bx >> 1));
        uint P[4][2];
        #pragma unroll
        for (int m = 0; m < 4; ++m) {
            const ushort cr[4] = { cvn[m].x, cvn[m].y, cvn[m].z, cvn[m].w };
            float wv4[4];
            #pragma unroll
            for (int r = 0; r < 4; ++r) {
                const float adc = acc[m][r];
                float wv = __expf(-adc);
                float pv = __builtin_amdgcn_rcpf(wv);
                float mm = (cr[r] == cls_i) ? 1.f : 0.f;
                if (isDiag) {
                    const bool nd = ((J0 + m * 16 + lg * 4 + r) != gi);
                    wv = nd ? wv : 0.f;
                    pv = nd ? pv : 0.f;
                    mm = nd ? mm : 0.f;
                }
                s_acc += wv;
                d_acc += pv;
                a_acc = fmaf(mm, adc, a_acc);
                b_acc += mm;
                wv4[r] = wv;
            }
            P[m][0] = cvtpk(wv4[0], wv4[1]);
            P[m][1] = cvtpk(wv4[2], wv4[3]);
        }

        // ---- prefetch next tile (this parity): cls + aJ slice-0; 2nd-half bD ----
        if (jt + 2 < jt_per) {
            const int jb = (J0 + 128) & (kB - 1);
            #pragma unroll
            for (int m = 0; m < 4; ++m)
                cvn[m] = *(const ushort4*)&cls[jb + m * 16 + lg * 4];
            const size_t xfJn = (size_t)((J0 + 128) >> 4) * 2048 + lane * 8;
            #pragma unroll
            for (int m = 0; m < 4; ++m)
                aJn[m] = *(const bf16x8*)&XF[xfJn + (size_t)m * 2048];
        }
        bf16x8 bDb[4][2];
        #pragma unroll
        for (int n = 0; n < 4; ++n)
            #pragma unroll
            for (int ks = 0; ks < 2; ++ks)
                bDb[n][ks] = *(const bf16x8*)&DF[dfJ + ((n + 4) * 2 + ks) * 512];

        // ---- in-register P redistribution -> PV A-frags ----
        bf16x8 pa[2];
        #pragma unroll
        for (int ks = 0; ks < 2; ++ks) {
            const uint lo0 = (uint)__shfl((int)P[2 * ks][0],     srcA, 64);
            const uint hi0 = (uint)__shfl((int)P[2 * ks + 1][0], srcA, 64);
            const uint lo1 = (uint)__shfl((int)P[2 * ks][1],     srcA, 64);
            const uint hi1 = (uint)__shfl((int)P[2 * ks + 1][1], srcA, 64);
            const uint lo2 = (uint)__shfl((int)P[2 * ks][0],     srcB, 64);
            const uint hi2 = (uint)__shfl((int)P[2 * ks + 1][0], srcB, 64);
            const uint lo3 = (uint)__shfl((int)P[2 * ks][1],     srcB, 64);
            const uint hi3 = (uint)__shfl((int)P[2 * ks + 1][1], srcB, 64);
            U16B u;
            u.u.x = hiSel ? hi0 : lo0;
            u.u.y = hiSel ? hi1 : lo1;
            u.u.z = hiSel ? hi2 : lo2;
            u.u.w = hiSel ? hi3 : lo3;
            pa[ks] = u.v;
        }

        // ---- PV ----
        #pragma unroll
        for (int ks = 0; ks < 2; ++ks)
            #pragma unroll
            for (int n = 0; n < 4; ++n)
                numacc[n] = __builtin_amdgcn_mfma_f32_16x16x32_bf16(
                    pa[ks], bDa[n][ks], numacc[n], 0, 0, 0);
        #pragma unroll
        for (int ks = 0; ks < 2; ++ks)
            #pragma unroll
            for (int n = 0; n < 4; ++n)
                numacc[n + 4] = __builtin_amdgcn_mfma_f32_16x16x32_bf16(
                    pa[ks], bDb[n][ks], numacc[n + 4], 0, 0, 0);
    }

    // ---- per-wave scalar reduce across lg groups ----
    float s = s_acc, d = d_acc, a = a_acc, b = b_acc;
    #pragma unroll
    for (int off = 16; off <= 32; off <<= 1) {
        s += __shfl_xor(s, off, 64);
        d += __shfl_xor(d, off, 64);
        a += __shfl_xor(a, off, 64);
        b += __shfl_xor(b, off, 64);
    }

    // ---- cross-parity reduction: jp=1 publishes, jp=0 merges + stores ----
    if (jp == 1) {
        #pragma unroll
        for (int n = 0; n < 8; ++n)
            #pragma unroll
            for (int r = 0; r < 4; ++r)
                RED[ip][lg * 4 + r][n * 16 + l15] = numacc[n][r];
        if (lane < 16) {
            SC[ip][0][lane] = s; SC[ip][1][lane] = d;
            SC[ip][2][lane] = a; SC[ip][3][lane] = b;
        }
    }
    __syncthreads();
    if (jp == 0) {
        if (lane < 16) {
            const size_t o = (size_t)chunk * kN + gi;
            s_part[o] = s + SC[ip][0][lane];
            d_part[o] = d + SC[ip][1][lane];
            a_part[o] = a + SC[ip][2][lane];
            b_part[o] = b + SC[ip][3][lane];
        }
        #pragma unroll
        for (int n = 0; n < 8; ++n)
            #pragma unroll
            for (int r = 0; r < 4; ++r) {
                const float v = numacc[n][r] + RED[ip][lg * 4 + r][n * 16 + l15];
                RED[ip][lg * 4 + r][n * 16 + l15] = v;   // same-wave rewrite
            }
        // bf16 pack + contiguous nontemporal stores (1KB/row-group)
        const int c8 = (lane & 15) * 8;
        #pragma unroll
        for (int p = 0; p < 4; ++p) {
            const int row = p * 4 + (lane >> 4);
            const float* src = &RED[ip][row][c8];
            u32x4 u;
            u.x = pack2(src[0], src[1]);
            u.y = pack2(src[2], src[3]);
            u.z = pack2(src[4], src[5]);
            u.w = pack2(src[6], src[7]);
            __builtin_nontemporal_store(
                u, (u32x4*)&num_bf[((size_t)chunk * kN + I0w + row) * kD + c8]);
        }
    }
}

// Kernel B: per-row finish (no fences, no atomics)
__global__ __launch_bounds__(256)
void supcon_finish(const ushort* __restrict__ num_bf,
                   const float* __restrict__ s_part,
                   const float* __restrict__ d_part,
                   const float* __restrict__ a_part,
                   const float* __restrict__ b_part,
                   const float* __restrict__ Dp,
                   const float* __restrict__ Lp,
                   float* __restrict__ out,
                   float* __restrict__ mlpp,
                   int jchunks)
{
    const int t    = threadIdx.x;
    const int w    = t >> 6;
    const int lane = t & 63;
    const int row  = blockIdx.x * 4 + w;
    const int c0   = 2 * lane;

    float n0 = 0.f, n1 = 0.f, s = 0.f, den = 0.f, a = 0.f, b = 0.f;
    for (int ch = 0; ch < jchunks; ++ch) {
        const uint u = *(const uint*)&num_bf[((size_t)ch * kN + row) * kD + c0];
        n0 += bf2f((ushort)(u & 0xffffu));
        n1 += bf2f((ushort)(u >> 16));
        const int sb = ch * kN + row;
        s   += s_part[sb];
        den += d_part[sb];
        a   += a_part[sb];
        b   += b_part[sb];
    }
    const float* d2 = Dp + (size_t)(row & (kB - 1)) * kD;
    const float* l2 = Lp + (size_t)(row & (kB - 1)) * kD;
    const float2 dv = *(const float2*)&d2[c0];
    const float2 lv = *(const float2*)&l2[c0];
    const float inv_s = 1.0f / s;
    float z0 = 0.7f * (dv.x - n0 * inv_s) + 0.3f * lv.x;
    float z1 = 0.7f * (dv.y - n1 * inv_s) + 0.3f * lv.y;

    float mx = fmaxf(z0, z1);
    #pragma unroll
    for (int off = 32; off >= 1; off >>= 1) mx = fmaxf(mx, __shfl_xor(mx, off, 64));
    const float e0 = __expf(z0 - mx);
    const float e1 = __expf(z1 - mx);
    float sm = e0 + e1;
    #pragma unroll
    for (int off = 32; off >= 1; off >>= 1) sm += __shfl_xor(sm, off, 64);
    const float inv = 1.0f / sm;

    const float2 o2 = make_float2(e0 * inv, e1 * inv);
    *(float2*)&out[1 + (size_t)row * kD + c0] = o2;

    if (lane == 0)
        mlpp[row] = (a - b * __logf(den)) / (b + 1e-5f);
}

// Kernel C: loss = -mean(mlpp)
__global__ __launch_bounds__(256)
void supcon_loss(const float* __restrict__ mlpp, float* __restrict__ out)
{
    __shared__ float red[4];
    const int t = threadIdx.x;
    float v = 0.f;
    for (int i = t; i < kN; i += 256) v += mlpp[i];
    #pragma unroll
    for (int off = 32; off >= 1; off >>= 1) v += __shfl_xor(v, off, 64);
    if ((t & 63) == 0) red[t >> 6] = v;
    __syncthreads();
    if (t == 0)
        out[0] = -(red[0] + red[1] + red[2] + red[3]) * (1.0f / (float)kN);
}

extern "C" void kernel_launch(void* const* d_in, const int* in_sizes, int n_in,
                              void* d_out, int out_size, void* d_ws, size_t ws_size,
                              hipStream_t stream) {
    const float* feats = (const float*)d_in[0];  // [2048][2][128]
    const float* maskp = (const float*)d_in[1];  // [4096][4096]
    const float* Dp    = (const float*)d_in[2];  // [2048][128]
    const float* Lp    = (const float*)d_in[3];  // [2048][128]
    float* out = (float*)d_out;                  // [0]=loss, [1..]=D_hat

    ushort* XF  = (ushort*)d_ws;                          // 1 MB
    ushort* DF  = XF + (size_t)kN * kD;                   // 1 MB
    ushort* cls = DF + (size_t)kD * kN;                   // 4 KB
    ushort* nb_base = cls + 4096;                         // (pad to 8KB)

    auto need = [](int nc) -> size_t {
        return (size_t)kN * kD * 2 * 2                    // XF + DF
             + 4096 * 2                                   // cls (+pad)
             + (size_t)nc * kN * kD * 2                   // num partials (bf16)
             + (size_t)nc * kN * 4 * 4                    // s,d,a,b
             + (size_t)kN * 4;                            // mlpp
    };
    int nchunk = 8;
    while (nchunk > 1 && need(nchunk) > ws_size) nchunk >>= 1;

    ushort* num_bf = nb_base;
    float* s_part = (float*)(num_bf + (size_t)nchunk * kN * kD);
    float* d_part = s_part + (size_t)nchunk * kN;
    float* a_part = d_part + (size_t)nchunk * kN;
    float* b_part = a_part + (size_t)nchunk * kN;
    float* mlpp   = b_part + (size_t)nchunk * kN;

    const int jt_per = (kN / 64) / nchunk;               // even for nchunk<=32

    supcon_prep<<<192, 256, 0, stream>>>(feats, Dp, maskp, XF, DF, cls);
    supcon_main<<<dim3(kN / 32, nchunk), 256, 0, stream>>>(
        XF, DF, cls, num_bf, s_part, d_part, a_part, b_part, jt_per);
    supcon_finish<<<kN / 4, 256, 0, stream>>>(
        num_bf, s_part, d_part, a_part, b_part, Dp, Lp, out, mlpp, nchunk);
    supcon_loss<<<1, 256, 0, stream>>>(mlpp, out);
}

// Round 15
// 49.839 us; speedup vs baseline: 2.4683x; 2.4683x over previous
//
#include <hip/hip_runtime.h>
#include <cstddef>
#include <cstdint>

// SupConLoss fused: MFMA + fragment-major loads + j-parity wave split +
// class-id mask (4KB L1-resident table) + cross-iteration aJ slice-0
// prefetch. launch_bounds(256,2) -- the ONLY bound that has produced a
// no-spill allocation for this kernel (VGPR ~108; (256,4) forced 64 VGPR
// and 420MB of scratch traffic; amdgpu_waves_per_eu was ignored).
// Separate loss kernel (NO device fences -- a per-block __threadfence ticket
// cost 90us in L2 writebacks on the non-coherent per-XCD L2s).
//
// Math (row-max cancels exactly):
//   num_i = sum_{j!=i} e^{-adc_ij} D2_j, s_i = sum_{j!=i} e^{-adc_ij}
//   den_i = sum_{j!=i} e^{+adc_ij},      a_i = sum m_ij adc_ij, b_i = sum m_ij
//   D_hat = softmax(0.7*(D2 - num/s) + 0.3*L2); loss = -mean((a - b*log den)/(b+1e-5))
// mask[i][j] = (cls[i&2047]==cls[j&2047]); cls[r] = first-set column of mask
// row r (diagonal guarantees existence).
//
//   XF[tile16][ks4][lane64][8]     : X*(1/sqrt(T)) bf16 fragments
//   DF[jtile64][n8*ks2][lane64][8] : D2^T bf16 fragments (PV B operand)
//   cls[2048]                      : u16 class representatives

namespace {
constexpr int   kN   = 4096;
constexpr int   kB   = 2048;
constexpr int   kD   = 128;
constexpr float kSc  = 3.77964473f;   // 1/sqrt(0.07); kSc*kSc = 1/T
}

typedef __attribute__((ext_vector_type(8))) short bf16x8;
typedef __attribute__((ext_vector_type(4))) float f32x4;
typedef __attribute__((ext_vector_type(4))) uint  u32x4;
typedef unsigned long long ull;

union U16B { uint4 u; bf16x8 v; };

__device__ __forceinline__ ushort f2bf(float x) {  // RNE f32->bf16 (finite)
    union { float f; uint u; } v; v.f = x;
    return (ushort)((v.u + 0x7FFFu + ((v.u >> 16) & 1u)) >> 16);
}
__device__ __forceinline__ uint pack2(float a, float b) {
    return (uint)f2bf(a) | ((uint)f2bf(b) << 16);
}
__device__ __forceinline__ uint cvtpk(float a, float b) {  // {lo=bf(a), hi=bf(b)}
    uint r;
    asm("v_cvt_pk_bf16_f32 %0, %1, %2" : "=v"(r) : "v"(a), "v"(b));
    return r;
}
__device__ __forceinline__ float bf2f(ushort u) {
    union { float f; uint x; } v; v.x = (uint)u << 16; return v.f;
}

// ---- prep: b<64: XF ; b<128: DF (LDS transpose) ; b<192: cls extraction ----
__global__ __launch_bounds__(256)
void supcon_prep(const float* __restrict__ feats, const float* __restrict__ Dp,
                 const float* __restrict__ maskp,
                 ushort* __restrict__ XF, ushort* __restrict__ DF,
                 ushort* __restrict__ cls)
{
    __shared__ float sh[64][129];
    const int b = blockIdx.x, t = threadIdx.x;
    const int lane = t & 63, l15 = lane & 15, lg = lane >> 4;

    if (b < 64) {
        const int tile = b * 4 + (t >> 6);
        const int i = tile * 16 + l15;
        const float* rp = feats + (size_t)(i & (kB - 1)) * 256 + (i >> 11) * 128;
        #pragma unroll
        for (int ks = 0; ks < 4; ++ks) {
            const float4 v0 = *(const float4*)(rp + ks * 32 + lg * 8);
            const float4 v1 = *(const float4*)(rp + ks * 32 + lg * 8 + 4);
            uint4 u;
            u.x = pack2(v0.x * kSc, v0.y * kSc); u.y = pack2(v0.z * kSc, v0.w * kSc);
            u.z = pack2(v1.x * kSc, v1.y * kSc); u.w = pack2(v1.z * kSc, v1.w * kSc);
            *(uint4*)&XF[(size_t)tile * 2048 + ks * 512 + lane * 8] = u;
        }
    } else if (b < 128) {
        const int jt = b - 64;
        const int r = t >> 2, c0 = (t & 3) * 32;
        const float* dp = Dp + (size_t)((jt * 64 + r) & (kB - 1)) * kD + c0;
        #pragma unroll
        for (int q = 0; q < 8; ++q) {
            const float4 v = *(const float4*)(dp + q * 4);
            sh[r][c0 + q * 4 + 0] = v.x; sh[r][c0 + q * 4 + 1] = v.y;
            sh[r][c0 + q * 4 + 2] = v.z; sh[r][c0 + q * 4 + 3] = v.w;
        }
        __syncthreads();
        #pragma unroll
        for (int k4 = 0; k4 < 4; ++k4) {
            const int U = k4 * 256 + t;
            const int nk = U >> 6;
            const int n = nk >> 1, ks = nk & 1;
            ushort e[8];
            #pragma unroll
            for (int ee = 0; ee < 8; ++ee)
                e[ee] = f2bf(sh[ks * 32 + lg * 8 + ee][n * 16 + l15]);
            uint4 u;
            u.x = (uint)e[0] | ((uint)e[1] << 16);
            u.y = (uint)e[2] | ((uint)e[3] << 16);
            u.z = (uint)e[4] | ((uint)e[5] << 16);
            u.w = (uint)e[6] | ((uint)e[7] << 16);
            *(uint4*)&DF[(size_t)jt * 8192 + (size_t)U * 8] = u;
        }
    } else {
        // cls: first-set column per mask row (8 rows per wave)
        const int wid = (b - 128) * 4 + (t >> 6);   // 0..255
        for (int rr = 0; rr < 8; ++rr) {
            const int row = wid * 8 + rr;
            const float* mrow = maskp + (size_t)row * kN;
            int found = -1;
            for (int q = 0; q < 8 && found < 0; ++q) {
                const float4 v = *(const float4*)(mrow + q * 256 + lane * 4);
                const ull b0 = __ballot(v.x != 0.f);
                const ull b1 = __ballot(v.y != 0.f);
                const ull b2 = __ballot(v.z != 0.f);
                const ull b3 = __ballot(v.w != 0.f);
                const ull any = b0 | b1 | b2 | b3;
                if (any) {
                    const int l0 = (int)__builtin_ctzll(any);
                    const int e0 = ((b0 >> l0) & 1ull) ? 0 : ((b1 >> l0) & 1ull) ? 1
                                 : ((b2 >> l0) & 1ull) ? 2 : 3;
                    found = q * 256 + l0 * 4 + e0;
                }
            }
            if (lane == 0) cls[row] = (ushort)found;
        }
    }
}

// ---- main: 256 thr = (2 i-subtiles) x (2 j-parities), 32 i-rows/block ----
__global__ __launch_bounds__(256, 2)
void supcon_main(const ushort* __restrict__ XF,
                 const ushort* __restrict__ DF,
                 const ushort* __restrict__ cls,
                 ushort* __restrict__ num_bf,    // [nchunk][4096][128] bf16
                 float* __restrict__ s_part,
                 float* __restrict__ d_part,
                 float* __restrict__ a_part,
                 float* __restrict__ b_part,
                 int jt_per)                     // must be even
{
    __shared__ float RED[2][16][132];
    __shared__ float SC[2][4][16];

    const int t    = threadIdx.x;
    const int lane = t & 63;
    const int l15  = lane & 15;
    const int lg   = lane >> 4;
    const int w    = t >> 6;
    const int ip   = w >> 1;            // i-subtile
    const int jp   = w & 1;             // j-parity
    const int bx   = blockIdx.x;        // 0..127 (32-row i-block)
    const int I0w  = bx * 32 + ip * 16;
    const int gi   = I0w + l15;
    const int chunk = blockIdx.y;
    const int Jbase = chunk * (jt_per * 64);

    bf16x8 bI[4];
    {
        const size_t xfI = (size_t)(bx * 2 + ip) * 2048 + lane * 8;
        #pragma unroll
        for (int ks = 0; ks < 4; ++ks)
            bI[ks] = *(const bf16x8*)&XF[xfI + ks * 512];
    }
    const ushort cls_i = cls[gi & (kB - 1)];

    f32x4 numacc[8];
    #pragma unroll
    for (int n = 0; n < 8; ++n) numacc[n] = (f32x4){0.f, 0.f, 0.f, 0.f};
    float s_acc = 0.f, d_acc = 0.f, a_acc = 0.f, b_acc = 0.f;

    const int srcA = l15 | (((lg << 1) & 3) << 4);
    const int srcB = l15 | ((((lg << 1) | 1) & 3) << 4);
    const bool hiSel = (lg >= 2);

    ushort4 cvn[4];
    bf16x8 aJn[4];                       // next tile's aJ slice-0 (prefetch)
    {
        const int jb = (Jbase + jp * 64) & (kB - 1);
        #pragma unroll
        for (int m = 0; m < 4; ++m)
            cvn[m] = *(const ushort4*)&cls[jb + m * 16 + lg * 4];
        const size_t xfJ0 = (size_t)((Jbase + jp * 64) >> 4) * 2048 + lane * 8;
        #pragma unroll
        for (int m = 0; m < 4; ++m)
            aJn[m] = *(const bf16x8*)&XF[xfJ0 + (size_t)m * 2048];
    }

    for (int jt = jp; jt < jt_per; jt += 2) {
        const int J0 = Jbase + jt * 64;

        // ---- QK^T: slice-0 comes from cross-iteration prefetch ----
        f32x4 acc[4];
        #pragma unroll
        for (int m = 0; m < 4; ++m) acc[m] = (f32x4){0.f, 0.f, 0.f, 0.f};
        const size_t xfJ = (size_t)(J0 >> 4) * 2048 + lane * 8;
        bf16x8 aJ2[2][4];
        #pragma unroll
        for (int m = 0; m < 4; ++m)
            aJ2[0][m] = aJn[m];
        #pragma unroll
        for (int ks = 0; ks < 4; ++ks) {
            if (ks < 3) {
                #pragma unroll
                for (int m = 0; m < 4; ++m)
                    aJ2[(ks + 1) & 1][m] =
                        *(const bf16x8*)&XF[xfJ + (size_t)m * 2048 + (ks + 1) * 512];
            }
            #pragma unroll
            for (int m = 0; m < 4; ++m)
                acc[m] = __builtin_amdgcn_mfma_f32_16x16x32_bf16(
                    aJ2[ks & 1][m], bI[ks], acc[m], 0, 0, 0);
        }

        // ---- first-half bD ----
        const size_t dfJ = (size_t)(J0 >> 6) * 8192 + lane * 8;
        bf16x8 bDa[4][2];
        #pragma unroll
        for (int n = 0; n < 4; ++n)
            #pragma unroll
            for (int ks = 0; ks < 2; ++ks)
                bDa[n][ks] = *(const bf16x8*)&DF[dfJ + (n * 2 + ks) * 512];

        // ---- exp, scalar partials, pack P (adc = acc, pre-scaled X) ----
        const bool isDiag = ((J0 >> 6) == (bx >> 1));
        uint P[4][2];
        #pragma unroll
        for (int m = 0; m < 4; ++m) {
            const ushort cr[4] = { cvn[m].x, cvn[m].y, cvn[m].z, cvn[m].w };
            float wv4[4];
            #pragma unroll
            for (int r = 0; r < 4; ++r) {
                const float adc = acc[m][r];
                float wv = __expf(-adc);
                float pv = __builtin_amdgcn_rcpf(wv);
                float mm = (cr[r] == cls_i) ? 1.f : 0.f;
                if (isDiag) {
                    const bool nd = ((J0 + m * 16 + lg * 4 + r) != gi);
                    wv = nd ? wv : 0.f;
                    pv = nd ? pv : 0.f;
                    mm = nd ? mm : 0.f;
                }
                s_acc += wv;
                d_acc += pv;
                a_acc = fmaf(mm, adc, a_acc);
                b_acc += mm;
                wv4[r] = wv;
            }
            P[m][0] = cvtpk(wv4[0], wv4[1]);
            P[m][1] = cvtpk(wv4[2], wv4[3]);
        }

        // ---- prefetch next tile (this parity): cls + aJ slice-0; 2nd-half bD ----
        if (jt + 2 < jt_per) {
            const int jb = (J0 + 128) & (kB - 1);
            #pragma unroll
            for (int m = 0; m < 4; ++m)
                cvn[m] = *(const ushort4*)&cls[jb + m * 16 + lg * 4];
            const size_t xfJn = (size_t)((J0 + 128) >> 4) * 2048 + lane * 8;
            #pragma unroll
            for (int m = 0; m < 4; ++m)
                aJn[m] = *(const bf16x8*)&XF[xfJn + (size_t)m * 2048];
        }
        bf16x8 bDb[4][2];
        #pragma unroll
        for (int n = 0; n < 4; ++n)
            #pragma unroll
            for (int ks = 0; ks < 2; ++ks)
                bDb[n][ks] = *(const bf16x8*)&DF[dfJ + ((n + 4) * 2 + ks) * 512];

        // ---- in-register P redistribution -> PV A-frags ----
        bf16x8 pa[2];
        #pragma unroll
        for (int ks = 0; ks < 2; ++ks) {
            const uint lo0 = (uint)__shfl((int)P[2 * ks][0],     srcA, 64);
            const uint hi0 = (uint)__shfl((int)P[2 * ks + 1][0], srcA, 64);
            const uint lo1 = (uint)__shfl((int)P[2 * ks][1],     srcA, 64);
            const uint hi1 = (uint)__shfl((int)P[2 * ks + 1][1], srcA, 64);
            const uint lo2 = (uint)__shfl((int)P[2 * ks][0],     srcB, 64);
            const uint hi2 = (uint)__shfl((int)P[2 * ks + 1][0], srcB, 64);
            const uint lo3 = (uint)__shfl((int)P[2 * ks][1],     srcB, 64);
            const uint hi3 = (uint)__shfl((int)P[2 * ks + 1][1], srcB, 64);
            U16B u;
            u.u.x = hiSel ? hi0 : lo0;
            u.u.y = hiSel ? hi1 : lo1;
            u.u.z = hiSel ? hi2 : lo2;
            u.u.w = hiSel ? hi3 : lo3;
            pa[ks] = u.v;
        }

        // ---- PV ----
        #pragma unroll
        for (int ks = 0; ks < 2; ++ks)
            #pragma unroll
            for (int n = 0; n < 4; ++n)
                numacc[n] = __builtin_amdgcn_mfma_f32_16x16x32_bf16(
                    pa[ks], bDa[n][ks], numacc[n], 0, 0, 0);
        #pragma unroll
        for (int ks = 0; ks < 2; ++ks)
            #pragma unroll
            for (int n = 0; n < 4; ++n)
                numacc[n + 4] = __builtin_amdgcn_mfma_f32_16x16x32_bf16(
                    pa[ks], bDb[n][ks], numacc[n + 4], 0, 0, 0);
    }

    // ---- per-wave scalar reduce across lg groups ----
    float s = s_acc, d = d_acc, a = a_acc, b = b_acc;
    #pragma unroll
    for (int off = 16; off <= 32; off <<= 1) {
        s += __shfl_xor(s, off, 64);
        d += __shfl_xor(d, off, 64);
        a += __shfl_xor(a, off, 64);
        b += __shfl_xor(b, off, 64);
    }

    // ---- cross-parity reduction: jp=1 publishes, jp=0 merges + stores ----
    if (jp == 1) {
        #pragma unroll
        for (int n = 0; n < 8; ++n)
            #pragma unroll
            for (int r = 0; r < 4; ++r)
                RED[ip][lg * 4 + r][n * 16 + l15] = numacc[n][r];
        if (lane < 16) {
            SC[ip][0][lane] = s; SC[ip][1][lane] = d;
            SC[ip][2][lane] = a; SC[ip][3][lane] = b;
        }
    }
    __syncthreads();
    if (jp == 0) {
        if (lane < 16) {
            const size_t o = (size_t)chunk * kN + gi;
            s_part[o] = s + SC[ip][0][lane];
            d_part[o] = d + SC[ip][1][lane];
            a_part[o] = a + SC[ip][2][lane];
            b_part[o] = b + SC[ip][3][lane];
        }
        #pragma unroll
        for (int n = 0; n < 8; ++n)
            #pragma unroll
            for (int r = 0; r < 4; ++r) {
                const float v = numacc[n][r] + RED[ip][lg * 4 + r][n * 16 + l15];
                RED[ip][lg * 4 + r][n * 16 + l15] = v;   // same-wave rewrite
            }
        // bf16 pack + contiguous nontemporal stores (1KB/row-group)
        const int c8 = (lane & 15) * 8;
        #pragma unroll
        for (int p = 0; p < 4; ++p) {
            const int row = p * 4 + (lane >> 4);
            const float* src = &RED[ip][row][c8];
            u32x4 u;
            u.x = pack2(src[0], src[1]);
            u.y = pack2(src[2], src[3]);
            u.z = pack2(src[4], src[5]);
            u.w = pack2(src[6], src[7]);
            __builtin_nontemporal_store(
                u, (u32x4*)&num_bf[((size_t)chunk * kN + I0w + row) * kD + c8]);
        }
    }
}

// Kernel B: per-row finish (no fences, no atomics)
__global__ __launch_bounds__(256)
void supcon_finish(const ushort* __restrict__ num_bf,
                   const float* __restrict__ s_part,
                   const float* __restrict__ d_part,
                   const float* __restrict__ a_part,
                   const float* __restrict__ b_part,
                   const float* __restrict__ Dp,
                   const float* __restrict__ Lp,
                   float* __restrict__ out,
                   float* __restrict__ mlpp,
                   int jchunks)
{
    const int t    = threadIdx.x;
    const int w    = t >> 6;
    const int lane = t & 63;
    const int row  = blockIdx.x * 4 + w;
    const int c0   = 2 * lane;

    float n0 = 0.f, n1 = 0.f, s = 0.f, den = 0.f, a = 0.f, b = 0.f;
    for (int ch = 0; ch < jchunks; ++ch) {
        const uint u = *(const uint*)&num_bf[((size_t)ch * kN + row) * kD + c0];
        n0 += bf2f((ushort)(u & 0xffffu));
        n1 += bf2f((ushort)(u >> 16));
        const int sb = ch * kN + row;
        s   += s_part[sb];
        den += d_part[sb];
        a   += a_part[sb];
        b   += b_part[sb];
    }
    const float* d2 = Dp + (size_t)(row & (kB - 1)) * kD;
    const float* l2 = Lp + (size_t)(row & (kB - 1)) * kD;
    const float2 dv = *(const float2*)&d2[c0];
    const float2 lv = *(const float2*)&l2[c0];
    const float inv_s = 1.0f / s;
    float z0 = 0.7f * (dv.x - n0 * inv_s) + 0.3f * lv.x;
    float z1 = 0.7f * (dv.y - n1 * inv_s) + 0.3f * lv.y;

    float mx = fmaxf(z0, z1);
    #pragma unroll
    for (int off = 32; off >= 1; off >>= 1) mx = fmaxf(mx, __shfl_xor(mx, off, 64));
    const float e0 = __expf(z0 - mx);
    const float e1 = __expf(z1 - mx);
    float sm = e0 + e1;
    #pragma unroll
    for (int off = 32; off >= 1; off >>= 1) sm += __shfl_xor(sm, off, 64);
    const float inv = 1.0f / sm;

    const float2 o2 = make_float2(e0 * inv, e1 * inv);
    *(float2*)&out[1 + (size_t)row * kD + c0] = o2;

    if (lane == 0)
        mlpp[row] = (a - b * __logf(den)) / (b + 1e-5f);
}

// Kernel C: loss = -mean(mlpp)
__global__ __launch_bounds__(256)
void supcon_loss(const float* __restrict__ mlpp, float* __restrict__ out)
{
    __shared__ float red[4];
    const int t = threadIdx.x;
    float v = 0.f;
    for (int i = t; i < kN; i += 256) v += mlpp[i];
    #pragma unroll
    for (int off = 32; off >= 1; off >>= 1) v += __shfl_xor(v, off, 64);
    if ((t & 63) == 0) red[t >> 6] = v;
    __syncthreads();
    if (t == 0)
        out[0] = -(red[0] + red[1] + red[2] + red[3]) * (1.0f / (float)kN);
}

extern "C" void kernel_launch(void* const* d_in, const int* in_sizes, int n_in,
                              void* d_out, int out_size, void* d_ws, size_t ws_size,
                              hipStream_t stream) {
    const float* feats = (const float*)d_in[0];  // [2048][2][128]
    const float* maskp = (const float*)d_in[1];  // [4096][4096]
    const float* Dp    = (const float*)d_in[2];  // [2048][128]
    const float* Lp    = (const float*)d_in[3];  // [2048][128]
    float* out = (float*)d_out;                  // [0]=loss, [1..]=D_hat

    ushort* XF  = (ushort*)d_ws;                          // 1 MB
    ushort* DF  = XF + (size_t)kN * kD;                   // 1 MB
    ushort* cls = DF + (size_t)kD * kN;                   // 4 KB
    ushort* nb_base = cls + 4096;                         // (pad to 8KB)

    auto need = [](int nc) -> size_t {
        return (size_t)kN * kD * 2 * 2                    // XF + DF
             + 4096 * 2                                   // cls (+pad)
             + (size_t)nc * kN * kD * 2                   // num partials (bf16)
             + (size_t)nc * kN * 4 * 4                    // s,d,a,b
             + (size_t)kN * 4;                            // mlpp
    };
    int nchunk = 8;
    while (nchunk > 1 && need(nchunk) > ws_size) nchunk >>= 1;

    ushort* num_bf = nb_base;
    float* s_part = (float*)(num_bf + (size_t)nchunk * kN * kD);
    float* d_part = s_part + (size_t)nchunk * kN;
    float* a_part = d_part + (size_t)nchunk * kN;
    float* b_part = a_part + (size_t)nchunk * kN;
    float* mlpp   = b_part + (size_t)nchunk * kN;

    const int jt_per = (kN / 64) / nchunk;               // even for nchunk<=32

    supcon_prep<<<192, 256, 0, stream>>>(feats, Dp, maskp, XF, DF, cls);
    supcon_main<<<dim3(kN / 32, nchunk), 256, 0, stream>>>(
        XF, DF, cls, num_bf, s_part, d_part, a_part, b_part, jt_per);
    supcon_finish<<<kN / 4, 256, 0, stream>>>(
        num_bf, s_part, d_part, a_part, b_part, Dp, Lp, out, mlpp, nchunk);
    supcon_loss<<<1, 256, 0, stream>>>(mlpp, out);
}